// Round 1
// baseline (20768.213 us; speedup 1.0000x reference)
//
#include <hip/hip_runtime.h>

typedef _Float16 half8 __attribute__((ext_vector_type(8)));
typedef float f32x4 __attribute__((ext_vector_type(4)));

#define T_STEPS 512
#define NWG 16

__device__ __forceinline__ float sigm(float x){ return 1.f/(1.f+__expf(-x)); }
__device__ __forceinline__ float tanh_fast(float x){ float e=__expf(2.f*x); return 1.f - 2.f/(e+1.f); }

// ---- prep: W0 = [W_ih0 (K 0..63) | W_hh0 (K 64..319)] -> fragment-blocked fp16
// layout: [jt 0..63][kc 0..9][lane 0..63][8], lane: row = jt*16+(lane&15), k = kc*32+(lane>>4)*8+j
__global__ void prep_w0(const float* __restrict__ Wih, const float* __restrict__ Whh,
                        _Float16* __restrict__ dst){
  int idx = blockIdx.x*blockDim.x + threadIdx.x;
  if (idx >= 64*10*64) return;
  int lane = idx & 63;
  int kc = (idx >> 6) % 10;
  int jt = idx / 640;
  int row = jt*16 + (lane & 15);
  int k0 = kc*32 + (lane >> 4)*8;
  _Float16* d = dst + (size_t)idx*8;
#pragma unroll
  for (int j=0;j<8;j++){
    int k = k0 + j;
    float v = (k < 64) ? Wih[row*64 + k] : Whh[row*256 + (k - 64)];
    d[j] = (_Float16)v;
  }
}

// ---- prep: W1 = [W_ih1 (K 0..255) | W_hh1 (K 256..511)] -> [jt][kc 0..15][lane][8]
__global__ void prep_w1(const float* __restrict__ Wih, const float* __restrict__ Whh,
                        _Float16* __restrict__ dst){
  int idx = blockIdx.x*blockDim.x + threadIdx.x;
  if (idx >= 64*16*64) return;
  int lane = idx & 63;
  int kc = (idx >> 6) & 15;
  int jt = idx >> 10;
  int row = jt*16 + (lane & 15);
  int k0 = kc*32 + (lane >> 4)*8;
  _Float16* d = dst + (size_t)idx*8;
#pragma unroll
  for (int j=0;j<8;j++){
    int k = k0 + j;
    float v = (k < 256) ? Wih[row*256 + k] : Whh[row*256 + (k - 256)];
    d[j] = (_Float16)v;
  }
}

// ---- prep: x [B,T,64] fp32 -> xblk fp16 [t][wg][i 0..127][8]; i=(kk8*16+col), b=wg*16+col, k=kk8*8+j
__global__ void prep_x(const float* __restrict__ x, _Float16* __restrict__ xblk){
  int idx = blockIdx.x*blockDim.x + threadIdx.x;
  if (idx >= 512*16*128) return;
  int i = idx & 127;
  int wg = (idx >> 7) & 15;
  int t = idx >> 11;
  int col = i & 15, kk8 = i >> 4;
  int b = wg*16 + col;
  const float* src = x + ((size_t)b*512 + (size_t)t)*64 + kk8*8;
  _Float16* dst = xblk + (size_t)idx*8;
#pragma unroll
  for (int j=0;j<8;j++) dst[j] = (_Float16)src[j];
}

// ---- fused persistent 2-layer LSTM + head ----
// grid = 16 WGs (one per 16-batch slice), 512 threads (8 waves, wave w owns h-slice [w*32,w*32+32))
__global__ __launch_bounds__(512) void lstm_fused(
    const _Float16* __restrict__ W0blk,
    const _Float16* __restrict__ W1blk,
    const _Float16* __restrict__ xblk,
    const float* __restrict__ b_ih0, const float* __restrict__ b_hh0,
    const float* __restrict__ b_ih1, const float* __restrict__ b_hh1,
    const float* __restrict__ W_head, const float* __restrict__ b_head,
    float* __restrict__ out)
{
  // h buffers: fp16, blocked [kk8][col][8]: linear = (k>>3)*128 + col*8 + (k&7)
  __shared__ __align__(16) _Float16 h0buf[2][4096];
  __shared__ __align__(16) _Float16 h1buf[2][4096];
  __shared__ __align__(16) float bias_lds[2048];   // [layer][wave][tn][row16]
  __shared__ __align__(16) float hfinal[4096];     // [k][col] fp32 final h1

  const int tid = threadIdx.x;
  const int wave = tid >> 6;
  const int lane = tid & 63;
  const int wg = blockIdx.x;
  const int lcol = lane & 15;   // batch col within tile (N / D-col)
  const int lrow = lane >> 4;   // k-group for A/B, row-group for D

  for (int i = tid; i < 4096; i += 512){
    h0buf[0][i] = (_Float16)0.f; h0buf[1][i] = (_Float16)0.f;
    h1buf[0][i] = (_Float16)0.f; h1buf[1][i] = (_Float16)0.f;
  }
  for (int i = tid; i < 2048; i += 512){
    int layer = i >> 10; int j = i & 1023;
    int g = j >> 8, wv = (j >> 5) & 7, s = (j >> 4) & 1, rr = j & 15;
    float v = layer ? (b_ih1[j] + b_hh1[j]) : (b_ih0[j] + b_hh0[j]);
    bias_lds[layer*1024 + (wv*8 + (g*2 + s))*16 + rr] = v;
  }
  __syncthreads();

  f32x4 zero4 = {0.f,0.f,0.f,0.f};
  f32x4 c0[2] = {zero4, zero4};
  f32x4 c1[2] = {zero4, zero4};

  const _Float16* wa0_base = W0blk + (size_t)lane*8;
  const _Float16* wa1_base = W1blk + (size_t)lane*8;

  for (int t = 0; t < T_STEPS; ++t){
    const int qw = t & 1, qr = qw ^ 1;

    // ===== Layer 0: gates = [x_t | h0_{t-1}] (K=320) x W0^T =====
    half8 bf[16];
    const _Float16* xb = xblk + (size_t)(t*16 + wg) * 1024;
#pragma unroll
    for (int kc = 0; kc < 2; ++kc)
      bf[kc] = *(const half8*)(xb + ((kc*4 + lrow)*16 + lcol)*8);
#pragma unroll
    for (int kc = 2; kc < 10; ++kc)
      bf[kc] = *(const half8*)&h0buf[qr][((kc-2)*4 + lrow)*128 + lcol*8];

    f32x4 acc[8];
#pragma unroll
    for (int tn = 0; tn < 8; ++tn)
      acc[tn] = *(const f32x4*)&bias_lds[(wave*8 + tn)*16 + lrow*4];

#pragma unroll
    for (int kc = 0; kc < 10; ++kc){
#pragma unroll
      for (int tn = 0; tn < 8; ++tn){
        int jt = (tn>>1)*16 + wave*2 + (tn&1);
        half8 af = *(const half8*)(wa0_base + (size_t)(jt*10 + kc)*512);
        acc[tn] = __builtin_amdgcn_mfma_f32_16x16x32_f16(af, bf[kc], acc[tn], 0, 0, 0);
      }
    }

    float h0new[8];
#pragma unroll
    for (int s = 0; s < 2; ++s){
#pragma unroll
      for (int r = 0; r < 4; ++r){
        float ig = sigm(acc[0*2+s][r]);
        float fg = sigm(acc[1*2+s][r]);
        float gg = tanh_fast(acc[2*2+s][r]);
        float og = sigm(acc[3*2+s][r]);
        float c = fg*c0[s][r] + ig*gg;
        c0[s][r] = c;
        h0new[s*4+r] = og * tanh_fast(c);
      }
    }
#pragma unroll
    for (int s = 0; s < 2; ++s){
#pragma unroll
      for (int r = 0; r < 4; ++r){
        int nh = wave*32 + s*16 + lrow*4 + r;
        h0buf[qw][((nh>>3)*128) + lcol*8 + (nh&7)] = (_Float16)h0new[s*4+r];
      }
    }
    __syncthreads();   // h0_t visible to all waves

    // ===== Layer 1: gates = [h0_t | h1_{t-1}] (K=512) x W1^T =====
#pragma unroll
    for (int kc = 0; kc < 8; ++kc)
      bf[kc] = *(const half8*)&h0buf[qw][(kc*4 + lrow)*128 + lcol*8];
#pragma unroll
    for (int kc = 8; kc < 16; ++kc)
      bf[kc] = *(const half8*)&h1buf[qr][((kc-8)*4 + lrow)*128 + lcol*8];

#pragma unroll
    for (int tn = 0; tn < 8; ++tn)
      acc[tn] = *(const f32x4*)&bias_lds[1024 + (wave*8 + tn)*16 + lrow*4];

#pragma unroll
    for (int kc = 0; kc < 16; ++kc){
#pragma unroll
      for (int tn = 0; tn < 8; ++tn){
        int jt = (tn>>1)*16 + wave*2 + (tn&1);
        half8 af = *(const half8*)(wa1_base + (size_t)(jt*16 + kc)*512);
        acc[tn] = __builtin_amdgcn_mfma_f32_16x16x32_f16(af, bf[kc], acc[tn], 0, 0, 0);
      }
    }

#pragma unroll
    for (int s = 0; s < 2; ++s){
#pragma unroll
      for (int r = 0; r < 4; ++r){
        float ig = sigm(acc[0*2+s][r]);
        float fg = sigm(acc[1*2+s][r]);
        float gg = tanh_fast(acc[2*2+s][r]);
        float og = sigm(acc[3*2+s][r]);
        float c = fg*c1[s][r] + ig*gg;
        c1[s][r] = c;
        float h = og * tanh_fast(c);
        int nh = wave*32 + s*16 + lrow*4 + r;
        h1buf[qw][((nh>>3)*128) + lcol*8 + (nh&7)] = (_Float16)h;
        if (t == T_STEPS-1) hfinal[nh*16 + lcol] = h;
      }
    }
    __syncthreads();   // h1_t visible; also protects next step's buffer reuse
  }

  // ===== Head: logits[b, o] = h1_final . W_head[o,:] + b_head[o] =====
  for (int idx = tid; idx < 16*120; idx += 512){
    int b = idx / 120, o = idx - b*120;
    float s = b_head[o];
    const float* wh = W_head + o*256;
#pragma unroll 8
    for (int k = 0; k < 256; ++k)
      s += hfinal[k*16 + b] * wh[k];
    out[(size_t)(wg*16 + b)*120 + o] = s;
  }
}

extern "C" void kernel_launch(void* const* d_in, const int* in_sizes, int n_in,
                              void* d_out, int out_size, void* d_ws, size_t ws_size,
                              hipStream_t stream){
  const float* x     = (const float*)d_in[0];
  const float* W_ih0 = (const float*)d_in[1];
  const float* W_hh0 = (const float*)d_in[2];
  const float* b_ih0 = (const float*)d_in[3];
  const float* b_hh0 = (const float*)d_in[4];
  const float* W_ih1 = (const float*)d_in[5];
  const float* W_hh1 = (const float*)d_in[6];
  const float* b_ih1 = (const float*)d_in[7];
  const float* b_hh1 = (const float*)d_in[8];
  const float* W_head= (const float*)d_in[9];
  const float* b_head= (const float*)d_in[10];
  float* out = (float*)d_out;

  _Float16* W0blk = (_Float16*)d_ws;          // 64*10*64*8  = 327,680 halves
  _Float16* W1blk = W0blk + 327680;           // 64*16*64*8  = 524,288 halves
  _Float16* xblk  = W1blk + 524288;           // 512*16*128*8 = 8,388,608 halves

  hipLaunchKernelGGL(prep_w0, dim3(160), dim3(256), 0, stream, W_ih0, W_hh0, W0blk);
  hipLaunchKernelGGL(prep_w1, dim3(256), dim3(256), 0, stream, W_ih1, W_hh1, W1blk);
  hipLaunchKernelGGL(prep_x,  dim3(4096), dim3(256), 0, stream, x, xblk);
  hipLaunchKernelGGL(lstm_fused, dim3(NWG), dim3(512), 0, stream,
                     W0blk, W1blk, xblk, b_ih0, b_hh0, b_ih1, b_hh1, W_head, b_head, out);
}

// Round 3
// 3963.622 us; speedup vs baseline: 5.2397x; 5.2397x over previous
//
#include <hip/hip_runtime.h>

typedef _Float16 half_t;
typedef _Float16 half8 __attribute__((ext_vector_type(8)));
typedef float f32x4 __attribute__((ext_vector_type(4)));
typedef unsigned long long u64;
typedef unsigned int u32;

#define GROUPS 8
#define WPG 16
#define NWG 128
#define THREADS 512
#define TSTEPS 512

// ws layout (halves)
#define W0_HALVES (16*4*10*64*8)        // 327680
#define W1_HALVES (16*4*16*64*8)        // 524288
#define X_HALVES  (512*8*2048)          // 8388608
#define HG_HALVES (2*8*8192)            // 131072 per layer buffer (2 parities x 8 groups x 8192)

__device__ __forceinline__ float sigm(float x){ return 1.f/(1.f+__expf(-x)); }
__device__ __forceinline__ float tanh_fast(float x){ float e=__expf(2.f*x); return 1.f - 2.f/(e+1.f); }

// W0 slice blocks: [j 0..15][r 0..3][kc 0..9][lane 0..63][8]
// tile row tr = lane&15 -> gate = tr&3, h_local = tr>>2 ; global row = gate*256 + j*16 + r*4 + h_local
// k = kc*32 + (lane>>4)*8 + jj ; K layout = [x(64) | h0(256)]
__global__ void prep_w0(const float* __restrict__ Wih, const float* __restrict__ Whh,
                        half_t* __restrict__ dst){
  int idx = blockIdx.x*blockDim.x + threadIdx.x;
  if (idx >= 16*4*10*64) return;
  int lane = idx & 63;
  int kc = (idx >> 6) % 10;
  int r  = (idx / 640) & 3;
  int j  = idx / 2560;
  int tr = lane & 15, kg = lane >> 4;
  int grow = (tr&3)*256 + j*16 + r*4 + (tr>>2);
  int k0 = kc*32 + kg*8;
  half_t* d = dst + (size_t)idx*8;
#pragma unroll
  for (int jj=0;jj<8;jj++){
    int k = k0 + jj;
    float v = (k < 64) ? Wih[grow*64 + k] : Whh[grow*256 + (k - 64)];
    d[jj] = (half_t)v;
  }
}

// W1 slice blocks: [j][r][kc 0..15][lane][8], K layout = [h0(256) | h1(256)]
__global__ void prep_w1(const float* __restrict__ Wih, const float* __restrict__ Whh,
                        half_t* __restrict__ dst){
  int idx = blockIdx.x*blockDim.x + threadIdx.x;
  if (idx >= 16*4*16*64) return;
  int lane = idx & 63;
  int kc = (idx >> 6) & 15;
  int r  = (idx >> 10) & 3;
  int j  = idx >> 12;
  int tr = lane & 15, kg = lane >> 4;
  int grow = (tr&3)*256 + j*16 + r*4 + (tr>>2);
  int k0 = kc*32 + kg*8;
  half_t* d = dst + (size_t)idx*8;
#pragma unroll
  for (int jj=0;jj<8;jj++){
    int k = k0 + jj;
    float v = (k < 256) ? Wih[grow*256 + k] : Whh[grow*256 + (k - 256)];
    d[jj] = (half_t)v;
  }
}

// x -> [t][g][row8 0..7][b 0..31][8] fp16  (k = row8*8 + jj, b global = g*32 + b)
__global__ void prep_x(const float* __restrict__ x, half_t* __restrict__ xblk){
  int idx = blockIdx.x*blockDim.x + threadIdx.x;
  if (idx >= 512*8*8*32) return;
  int b = idx & 31;
  int row8 = (idx >> 5) & 7;
  int g = (idx >> 8) & 7;
  int t = idx >> 11;
  const float* src = x + ((size_t)(g*32+b)*512 + (size_t)t)*64 + row8*8;
  half_t* d = xblk + (size_t)idx*8;
#pragma unroll
  for (int jj=0;jj<8;jj++) d[jj] = (half_t)src[jj];
}

// persistent distributed 2-layer LSTM: 8 groups x 16 WGs; WG owns 16 h, 32 batch; L1 lags L0 by 1 step
__global__ __launch_bounds__(THREADS) void lstm_dist(
    const half_t* __restrict__ W0blk, const half_t* __restrict__ W1blk,
    const half_t* __restrict__ xblk,
    half_t* __restrict__ h0g, half_t* __restrict__ h1g,
    u32* __restrict__ flags,
    const float* __restrict__ b_ih0, const float* __restrict__ b_hh0,
    const float* __restrict__ b_ih1, const float* __restrict__ b_hh1,
    const float* __restrict__ W_head, const float* __restrict__ b_head,
    float* __restrict__ out)
{
  extern __shared__ char smem[];
  half_t* W0lds = (half_t*)smem;              // 20480 halves (40960 B)
  half_t* W1lds = (half_t*)(smem + 40960);    // 32768 halves (65536 B)
  half_t* h0lds = (half_t*)(smem + 106496);   // 8192 halves (16384 B)
  half_t* h1lds = (half_t*)(smem + 122880);   // 8192 halves
  half_t* xlds  = (half_t*)(smem + 139264);   // 2048 halves (4096 B)
  float*  blds  = (float*)(smem + 143360);    // 128 f32 (512 B)  -> total 143872 B

  const int tid = threadIdx.x;
  const int wave = tid >> 6, lane = tid & 63;
  const int lcol = lane & 15, lrow = lane >> 4;
  const int bid = blockIdx.x;
  const int g = bid >> 4, j = bid & 15;
  const int r = wave >> 1, bt = wave & 1;

  // one-time: weights + biases -> LDS
  {
    const u64* s0 = (const u64*)(W0blk + (size_t)j*20480);
    u64* d0 = (u64*)W0lds;
    for (int i = tid; i < 5120; i += THREADS) d0[i] = s0[i];
    const u64* s1 = (const u64*)(W1blk + (size_t)j*32768);
    u64* d1 = (u64*)W1lds;
    for (int i = tid; i < 8192; i += THREADS) d1[i] = s1[i];
    if (tid < 128){
      int layer = tid >> 6, rl = tid & 63;
      int grow = (rl&3)*256 + j*16 + (rl>>4)*4 + ((rl>>2)&3);
      blds[tid] = layer ? (b_ih1[grow]+b_hh1[grow]) : (b_ih0[grow]+b_hh0[grow]);
    }
  }
  __syncthreads();

  float c0 = 0.f, c1 = 0.f;
  const int hidx = j*16 + r*4 + lrow;   // lane's h index within group (0..255)
  const int bcol = bt*16 + lcol;        // lane's batch col within group (0..31)

  for (int p = 0; p <= TSTEPS; ++p){
    // ---- stage h0(p-1), h1(p-2), x(p) into LDS ----
    {
      const u64* h0s = (const u64*)(h0g + (size_t)((p+1)&1)*65536 + (size_t)g*8192);
      u64* h0d = (u64*)h0lds;
      for (int i = tid; i < 2048; i += THREADS)
        h0d[i] = __hip_atomic_load(h0s + i, __ATOMIC_RELAXED, __HIP_MEMORY_SCOPE_AGENT);
      const u64* h1s = (const u64*)(h1g + (size_t)(p&1)*65536 + (size_t)g*8192);
      u64* h1d = (u64*)h1lds;
      for (int i = tid; i < 2048; i += THREADS)
        h1d[i] = __hip_atomic_load(h1s + i, __ATOMIC_RELAXED, __HIP_MEMORY_SCOPE_AGENT);
      if (p < TSTEPS){
        const u64* xs = (const u64*)(xblk + ((size_t)p*8 + g)*2048);
        u64* xd = (u64*)xlds;
        for (int i = tid; i < 512; i += THREADS) xd[i] = xs[i];
      }
    }
    __syncthreads();

    // ---- L0: step p ----
    if (p < TSTEPS){
      f32x4 acc = *(const f32x4*)(blds + r*16 + lrow*4);
#pragma unroll
      for (int kc = 0; kc < 10; ++kc){
        half8 af = *(const half8*)(W0lds + ((size_t)((r*10 + kc)*64 + lane))*8);
        const half_t* bp = (kc < 2)
            ? (xlds + ((kc*4 + lrow)*32 + bcol)*8)
            : (h0lds + (((kc-2)*4 + lrow)*32 + bcol)*8);
        half8 bf = *(const half8*)bp;
        acc = __builtin_amdgcn_mfma_f32_16x16x32_f16(af, bf, acc, 0, 0, 0);
      }
      float ig = sigm(acc[0]), fg = sigm(acc[1]);
      float gg = tanh_fast(acc[2]), og = sigm(acc[3]);
      c0 = fg*c0 + ig*gg;
      float hv = og * tanh_fast(c0);
      half_t* dst = h0g + (size_t)(p&1)*65536 + (size_t)g*8192
                  + ((hidx>>3)*32 + bcol)*8 + (hidx&7);
      __hip_atomic_store(dst, (half_t)hv, __ATOMIC_RELAXED, __HIP_MEMORY_SCOPE_AGENT);
    }

    // ---- L1: step p-1 ----
    if (p >= 1){
      f32x4 acc = *(const f32x4*)(blds + 64 + r*16 + lrow*4);
#pragma unroll
      for (int kc = 0; kc < 16; ++kc){
        half8 af = *(const half8*)(W1lds + ((size_t)((r*16 + kc)*64 + lane))*8);
        const half_t* bp = (kc < 8)
            ? (h0lds + ((kc*4 + lrow)*32 + bcol)*8)
            : (h1lds + (((kc-8)*4 + lrow)*32 + bcol)*8);
        half8 bf = *(const half8*)bp;
        acc = __builtin_amdgcn_mfma_f32_16x16x32_f16(af, bf, acc, 0, 0, 0);
      }
      float ig = sigm(acc[0]), fg = sigm(acc[1]);
      float gg = tanh_fast(acc[2]), og = sigm(acc[3]);
      c1 = fg*c1 + ig*gg;
      float hv = og * tanh_fast(c1);
      half_t* dst = h1g + (size_t)((p+1)&1)*65536 + (size_t)g*8192
                  + ((hidx>>3)*32 + bcol)*8 + (hidx&7);
      __hip_atomic_store(dst, (half_t)hv, __ATOMIC_RELAXED, __HIP_MEMORY_SCOPE_AGENT);
    }

    // ---- group barrier (phase-indexed flags; syncthreads drains vmcnt first) ----
    __syncthreads();
    u32* fl = flags + ((size_t)p*GROUPS + g)*WPG;
    if (tid == 0)
      __hip_atomic_store(fl + j, 1u, __ATOMIC_RELEASE, __HIP_MEMORY_SCOPE_AGENT);
    if (tid < WPG){
      int spins = 0;
      while (__hip_atomic_load(fl + tid, __ATOMIC_RELAXED, __HIP_MEMORY_SCOPE_AGENT) == 0
             && spins < (1<<18)) { ++spins; __builtin_amdgcn_s_sleep(2); }
      __threadfence();   // acquire: order the spin-observed flags before LDS staging reads
    }
    __syncthreads();
  }

  // ---- head: logits for this WG's 2 batch cols (group batch 2j, 2j+1) ----
  {
    const u64* hs = (const u64*)(h1g + 65536 + (size_t)g*8192);  // h1(511) parity 1
    u64* hd = (u64*)h1lds;
    for (int i = tid; i < 2048; i += THREADS)
      hd[i] = __hip_atomic_load(hs + i, __ATOMIC_RELAXED, __HIP_MEMORY_SCOPE_AGENT);
    __syncthreads();
    if (tid < 240){
      int bl = 2*j + (tid >= 120 ? 1 : 0);
      int o = tid % 120;
      float s = b_head[o];
      const float* wr = W_head + (size_t)o*256;
#pragma unroll 4
      for (int k8 = 0; k8 < 32; ++k8){
        half8 hv = *(const half8*)(h1lds + (k8*32 + bl)*8);
#pragma unroll
        for (int jj = 0; jj < 8; ++jj)
          s += (float)hv[jj] * wr[k8*8 + jj];
      }
      out[((size_t)g*32 + bl)*120 + o] = s;
    }
  }
}

extern "C" void kernel_launch(void* const* d_in, const int* in_sizes, int n_in,
                              void* d_out, int out_size, void* d_ws, size_t ws_size,
                              hipStream_t stream){
  const float* x     = (const float*)d_in[0];
  const float* W_ih0 = (const float*)d_in[1];
  const float* W_hh0 = (const float*)d_in[2];
  const float* b_ih0 = (const float*)d_in[3];
  const float* b_hh0 = (const float*)d_in[4];
  const float* W_ih1 = (const float*)d_in[5];
  const float* W_hh1 = (const float*)d_in[6];
  const float* b_ih1 = (const float*)d_in[7];
  const float* b_hh1 = (const float*)d_in[8];
  const float* W_head= (const float*)d_in[9];
  const float* b_head= (const float*)d_in[10];
  float* out = (float*)d_out;

  half_t* W0blk = (half_t*)d_ws;
  half_t* W1blk = W0blk + W0_HALVES;
  half_t* xblk  = W1blk + W1_HALVES;
  half_t* h0g   = xblk + X_HALVES;
  half_t* h1g   = h0g + HG_HALVES;
  u32*    flags = (u32*)(h1g + HG_HALVES);
  // flags: 513 * 8 * 16 u32 = 262,656 B ; total ws use ~19.3 MB

  // zero the exchange buffers + flags every launch (replay-safe)
  (void)hipMemsetAsync(h0g, 0, (size_t)HG_HALVES*2*2, stream);     // h0g + h1g (contiguous)
  (void)hipMemsetAsync(flags, 0, (size_t)513*GROUPS*WPG*4, stream);

  hipLaunchKernelGGL(prep_w0, dim3(160), dim3(256), 0, stream, W_ih0, W_hh0, W0blk);
  hipLaunchKernelGGL(prep_w1, dim3(256), dim3(256), 0, stream, W_ih1, W_hh1, W1blk);
  hipLaunchKernelGGL(prep_x,  dim3(4096), dim3(256), 0, stream, x, xblk);

  (void)hipFuncSetAttribute((const void*)lstm_dist,
                            hipFuncAttributeMaxDynamicSharedMemorySize, 143872);

  hipLaunchKernelGGL(lstm_dist, dim3(NWG), dim3(THREADS), 143872, stream,
                     W0blk, W1blk, xblk, h0g, h1g, flags,
                     b_ih0, b_hh0, b_ih1, b_hh1, W_head, b_head, out);
}

// Round 4
// 3641.408 us; speedup vs baseline: 5.7033x; 1.0885x over previous
//
#include <hip/hip_runtime.h>

typedef _Float16 half_t;
typedef _Float16 half8 __attribute__((ext_vector_type(8)));
typedef float f32x4 __attribute__((ext_vector_type(4)));
typedef unsigned long long u64;
typedef u64 u64x2 __attribute__((ext_vector_type(2)));
typedef unsigned int u32;

#define GROUPS 8
#define WPG 16
#define NWG 128
#define THREADS 512
#define TSTEPS 512

// ws layout (halves)
#define W0_HALVES (16*4*10*64*8)        // 327680
#define W1_HALVES (16*4*16*64*8)        // 524288
#define X_HALVES  (512*8*2048)          // 8388608
#define HG_HALVES (2*8*8192)            // per layer buffer (2 parities x 8 groups x 8192)
#define HPAR 65536                      // halves per parity block (8 groups * 8192)

__device__ __forceinline__ float sigm(float x){ return 1.f/(1.f+__expf(-x)); }
__device__ __forceinline__ float tanh_fast(float x){ float e=__expf(2.f*x); return 1.f - 2.f/(e+1.f); }

// W0 slice blocks: [j 0..15][r 0..3][kc 0..9][lane 0..63][8]
// tile row tr = lane&15 -> gate = tr&3, h_local = tr>>2 ; global row = gate*256 + j*16 + r*4 + h_local
// k = kc*32 + (lane>>4)*8 + jj ; K layout = [x(64) | h0(256)]
__global__ void prep_w0(const float* __restrict__ Wih, const float* __restrict__ Whh,
                        half_t* __restrict__ dst){
  int idx = blockIdx.x*blockDim.x + threadIdx.x;
  if (idx >= 16*4*10*64) return;
  int lane = idx & 63;
  int kc = (idx >> 6) % 10;
  int r  = (idx / 640) & 3;
  int j  = idx / 2560;
  int tr = lane & 15, kg = lane >> 4;
  int grow = (tr&3)*256 + j*16 + r*4 + (tr>>2);
  int k0 = kc*32 + kg*8;
  half_t* d = dst + (size_t)idx*8;
#pragma unroll
  for (int jj=0;jj<8;jj++){
    int k = k0 + jj;
    float v = (k < 64) ? Wih[grow*64 + k] : Whh[grow*256 + (k - 64)];
    d[jj] = (half_t)v;
  }
}

// W1 slice blocks: [j][r][kc 0..15][lane][8], K layout = [h0(256) | h1(256)]
__global__ void prep_w1(const float* __restrict__ Wih, const float* __restrict__ Whh,
                        half_t* __restrict__ dst){
  int idx = blockIdx.x*blockDim.x + threadIdx.x;
  if (idx >= 16*4*16*64) return;
  int lane = idx & 63;
  int kc = (idx >> 6) & 15;
  int r  = (idx >> 10) & 3;
  int j  = idx >> 12;
  int tr = lane & 15, kg = lane >> 4;
  int grow = (tr&3)*256 + j*16 + r*4 + (tr>>2);
  int k0 = kc*32 + kg*8;
  half_t* d = dst + (size_t)idx*8;
#pragma unroll
  for (int jj=0;jj<8;jj++){
    int k = k0 + jj;
    float v = (k < 256) ? Wih[grow*256 + k] : Whh[grow*256 + (k - 256)];
    d[jj] = (half_t)v;
  }
}

// x -> [t][g][row8 0..7][b 0..31][8] fp16  (k = row8*8 + jj, b global = g*32 + b)
__global__ void prep_x(const float* __restrict__ x, half_t* __restrict__ xblk){
  int idx = blockIdx.x*blockDim.x + threadIdx.x;
  if (idx >= 512*8*8*32) return;
  int b = idx & 31;
  int row8 = (idx >> 5) & 7;
  int g = (idx >> 8) & 7;
  int t = idx >> 11;
  const float* src = x + ((size_t)(g*32+b)*512 + (size_t)t)*64 + row8*8;
  half_t* d = xblk + (size_t)idx*8;
#pragma unroll
  for (int jj=0;jj<8;jj++) d[jj] = (half_t)src[jj];
}

// persistent distributed 2-layer LSTM: 8 groups x 16 WGs; WG owns 16 h, 32 batch; L1 lags L0 by 1 step
__global__ __launch_bounds__(THREADS) void lstm_dist(
    const half_t* __restrict__ W0blk, const half_t* __restrict__ W1blk,
    const half_t* __restrict__ xblk,
    half_t* __restrict__ h0g, half_t* __restrict__ h1g,
    u32* __restrict__ cnt,
    const float* __restrict__ b_ih0, const float* __restrict__ b_hh0,
    const float* __restrict__ b_ih1, const float* __restrict__ b_hh1,
    const float* __restrict__ W_head, const float* __restrict__ b_head,
    float* __restrict__ out)
{
  extern __shared__ char smem[];
  half_t* W0lds = (half_t*)smem;               // 20480 halves (40960 B)
  half_t* W1lds = (half_t*)(smem + 40960);     // 32768 halves (65536 B)
  float*  blds  = (float*)(smem + 106496);     // 128 f32 (512 B)
  half_t* hfin  = (half_t*)(smem + 107008);    // 8192 halves (16384 B) -> total 123392 B

  const int tid = threadIdx.x;
  const int wave = tid >> 6, lane = tid & 63;
  const int lcol = lane & 15, lrow = lane >> 4;
  const int bid = blockIdx.x;
  const int g = bid >> 4, j = bid & 15;
  const int r = wave >> 1, bt = wave & 1;

  // one-time: weights + biases -> LDS
  {
    const u64* s0 = (const u64*)(W0blk + (size_t)j*20480);
    u64* d0 = (u64*)W0lds;
    for (int i = tid; i < 5120; i += THREADS) d0[i] = s0[i];
    const u64* s1 = (const u64*)(W1blk + (size_t)j*32768);
    u64* d1 = (u64*)W1lds;
    for (int i = tid; i < 8192; i += THREADS) d1[i] = s1[i];
    if (tid < 128){
      int layer = tid >> 6, rl = tid & 63;
      int grow = (rl&3)*256 + j*16 + (rl>>4)*4 + ((rl>>2)&3);
      blds[tid] = layer ? (b_ih1[grow]+b_hh1[grow]) : (b_ih0[grow]+b_hh0[grow]);
    }
  }
  __syncthreads();

  float c0 = 0.f, c1 = 0.f;
  const int hidx = j*16 + r*4 + lrow;   // lane's h index within group (0..255)
  const int bcol = bt*16 + lcol;        // lane's batch col within group (0..31)
  u32* my_cnt = cnt + g*64;             // 256B-padded per-group counter (warm, monotonic)

  for (int p = 0; p <= TSTEPS; ++p){
    const int qw = p & 1, qr = qw ^ 1;

    // ---- direct-to-register B fragments (no LDS round trip) ----
    // h0(p-1): parity qr; used by L0 (kc 2..9) AND L1 (kc 0..7) -- load once.
    u64x2 h0f[8], h1f[8];
    {
      const u64* h0s = (const u64*)(h0g + (size_t)qr*HPAR + (size_t)g*8192);
      const u64* h1s = (const u64*)(h1g + (size_t)qw*HPAR + (size_t)g*8192);
#pragma unroll
      for (int c = 0; c < 8; ++c){
        const u64* a0 = h0s + ((c*4 + lrow)*32 + bcol)*2;
        u64x2 t0;
        t0.x = __hip_atomic_load(a0,   __ATOMIC_RELAXED, __HIP_MEMORY_SCOPE_AGENT);
        t0.y = __hip_atomic_load(a0+1, __ATOMIC_RELAXED, __HIP_MEMORY_SCOPE_AGENT);
        h0f[c] = t0;
        const u64* a1 = h1s + ((c*4 + lrow)*32 + bcol)*2;
        u64x2 t1;
        t1.x = __hip_atomic_load(a1,   __ATOMIC_RELAXED, __HIP_MEMORY_SCOPE_AGENT);
        t1.y = __hip_atomic_load(a1+1, __ATOMIC_RELAXED, __HIP_MEMORY_SCOPE_AGENT);
        h1f[c] = t1;
      }
    }
    half8 xf2[2];
    if (p < TSTEPS){
      const half_t* xs = xblk + ((size_t)p*8 + g)*2048;
#pragma unroll
      for (int c = 0; c < 2; ++c)
        xf2[c] = *(const half8*)(xs + ((c*4 + lrow)*32 + bcol)*8);
    }

    // ---- L0: step p ----
    if (p < TSTEPS){
      f32x4 acc = *(const f32x4*)(blds + r*16 + lrow*4);
#pragma unroll
      for (int kc = 0; kc < 2; ++kc){
        half8 af = *(const half8*)(W0lds + ((size_t)((r*10 + kc)*64 + lane))*8);
        acc = __builtin_amdgcn_mfma_f32_16x16x32_f16(af, xf2[kc], acc, 0, 0, 0);
      }
#pragma unroll
      for (int kc = 2; kc < 10; ++kc){
        half8 af = *(const half8*)(W0lds + ((size_t)((r*10 + kc)*64 + lane))*8);
        half8 bf = __builtin_bit_cast(half8, h0f[kc-2]);
        acc = __builtin_amdgcn_mfma_f32_16x16x32_f16(af, bf, acc, 0, 0, 0);
      }
      float ig = sigm(acc[0]), fg = sigm(acc[1]);
      float gg = tanh_fast(acc[2]), og = sigm(acc[3]);
      c0 = fg*c0 + ig*gg;
      float hv = og * tanh_fast(c0);
      half_t* dst = h0g + (size_t)qw*HPAR + (size_t)g*8192
                  + ((hidx>>3)*32 + bcol)*8 + (hidx&7);
      __hip_atomic_store(dst, (half_t)hv, __ATOMIC_RELAXED, __HIP_MEMORY_SCOPE_AGENT);
    }

    // ---- L1: step p-1 ----
    if (p >= 1){
      f32x4 acc = *(const f32x4*)(blds + 64 + r*16 + lrow*4);
#pragma unroll
      for (int kc = 0; kc < 8; ++kc){
        half8 af = *(const half8*)(W1lds + ((size_t)((r*16 + kc)*64 + lane))*8);
        half8 bf = __builtin_bit_cast(half8, h0f[kc]);
        acc = __builtin_amdgcn_mfma_f32_16x16x32_f16(af, bf, acc, 0, 0, 0);
      }
#pragma unroll
      for (int kc = 8; kc < 16; ++kc){
        half8 af = *(const half8*)(W1lds + ((size_t)((r*16 + kc)*64 + lane))*8);
        half8 bf = __builtin_bit_cast(half8, h1f[kc-8]);
        acc = __builtin_amdgcn_mfma_f32_16x16x32_f16(af, bf, acc, 0, 0, 0);
      }
      float ig = sigm(acc[0]), fg = sigm(acc[1]);
      float gg = tanh_fast(acc[2]), og = sigm(acc[3]);
      c1 = fg*c1 + ig*gg;
      float hv = og * tanh_fast(c1);
      half_t* dst = h1g + (size_t)qr*HPAR + (size_t)g*8192
                  + ((hidx>>3)*32 + bcol)*8 + (hidx&7);
      __hip_atomic_store(dst, (half_t)hv, __ATOMIC_RELAXED, __HIP_MEMORY_SCOPE_AGENT);
    }

    // ---- group barrier: warm monotonic counter, single poller ----
    __syncthreads();   // all waves' h-stores drained (vmcnt 0) before arrive
    if (tid == 0){
      __hip_atomic_fetch_add(my_cnt, 1u, __ATOMIC_RELEASE, __HIP_MEMORY_SCOPE_AGENT);
      u32 target = (u32)(WPG*(p+1));
      int spins = 0;
      while (__hip_atomic_load(my_cnt, __ATOMIC_RELAXED, __HIP_MEMORY_SCOPE_AGENT) < target
             && spins < (1<<20)) ++spins;
      (void)__hip_atomic_load(my_cnt, __ATOMIC_ACQUIRE, __HIP_MEMORY_SCOPE_AGENT);
    }
    __builtin_amdgcn_sched_barrier(0);
    __syncthreads();
  }

  // ---- head: logits for this WG's 2 batch cols (group batch 2j, 2j+1) ----
  {
    const u64* hs = (const u64*)(h1g + HPAR + (size_t)g*8192);  // h1(511) lives in parity 1
    u64* hd = (u64*)hfin;
    for (int i = tid; i < 2048; i += THREADS)
      hd[i] = __hip_atomic_load(hs + i, __ATOMIC_RELAXED, __HIP_MEMORY_SCOPE_AGENT);
    __syncthreads();
    if (tid < 240){
      int bl = 2*j + (tid >= 120 ? 1 : 0);
      int o = tid % 120;
      float s = b_head[o];
      const float* wr = W_head + (size_t)o*256;
#pragma unroll 4
      for (int k8 = 0; k8 < 32; ++k8){
        half8 hv = *(const half8*)(hfin + (k8*32 + bl)*8);
#pragma unroll
        for (int jj = 0; jj < 8; ++jj)
          s += (float)hv[jj] * wr[k8*8 + jj];
      }
      out[((size_t)g*32 + bl)*120 + o] = s;
    }
  }
}

extern "C" void kernel_launch(void* const* d_in, const int* in_sizes, int n_in,
                              void* d_out, int out_size, void* d_ws, size_t ws_size,
                              hipStream_t stream){
  const float* x     = (const float*)d_in[0];
  const float* W_ih0 = (const float*)d_in[1];
  const float* W_hh0 = (const float*)d_in[2];
  const float* b_ih0 = (const float*)d_in[3];
  const float* b_hh0 = (const float*)d_in[4];
  const float* W_ih1 = (const float*)d_in[5];
  const float* W_hh1 = (const float*)d_in[6];
  const float* b_ih1 = (const float*)d_in[7];
  const float* b_hh1 = (const float*)d_in[8];
  const float* W_head= (const float*)d_in[9];
  const float* b_head= (const float*)d_in[10];
  float* out = (float*)d_out;

  half_t* W0blk = (half_t*)d_ws;
  half_t* W1blk = W0blk + W0_HALVES;
  half_t* xblk  = W1blk + W1_HALVES;
  half_t* h0g   = xblk + X_HALVES;
  half_t* h1g   = h0g + HG_HALVES;
  u32*    cnt   = (u32*)(h1g + HG_HALVES);   // 8 groups x 64 u32 (256B padded)

  // zero exchange buffers + counters every launch (graph-replay safe)
  (void)hipMemsetAsync(h0g, 0, (size_t)HG_HALVES*2*2, stream);   // h0g + h1g (contiguous)
  (void)hipMemsetAsync(cnt, 0, (size_t)GROUPS*64*4, stream);

  hipLaunchKernelGGL(prep_w0, dim3(160), dim3(256), 0, stream, W_ih0, W_hh0, W0blk);
  hipLaunchKernelGGL(prep_w1, dim3(256), dim3(256), 0, stream, W_ih1, W_hh1, W1blk);
  hipLaunchKernelGGL(prep_x,  dim3(4096), dim3(256), 0, stream, x, xblk);

  (void)hipFuncSetAttribute((const void*)lstm_dist,
                            hipFuncAttributeMaxDynamicSharedMemorySize, 123392);

  hipLaunchKernelGGL(lstm_dist, dim3(NWG), dim3(THREADS), 123392, stream,
                     W0blk, W1blk, xblk, h0g, h1g, cnt,
                     b_ih0, b_hh0, b_ih1, b_hh1, W_head, b_head, out);
}

// Round 5
// 1616.614 us; speedup vs baseline: 12.8467x; 2.2525x over previous
//
#include <hip/hip_runtime.h>

typedef _Float16 half_t;
typedef _Float16 half8 __attribute__((ext_vector_type(8)));
typedef float f32x4 __attribute__((ext_vector_type(4)));
typedef unsigned long long u64;
typedef unsigned int u32;

#define GROUPS 8
#define WPG 16
#define NWG 128
#define THREADS 512
#define TSTEPS 512

// ws layout (halves)
#define W0_HALVES (16*4*10*64*8)        // 327680
#define W1_HALVES (16*4*16*64*8)        // 524288
#define X_HALVES  (512*8*2048)          // 8388608
#define HX_U32    (2*GROUPS*8192)       // per layer: 2 ring slots x 8 groups x (256h x 32b)

__device__ __forceinline__ float sigm(float x){ return 1.f/(1.f+__expf(-x)); }
__device__ __forceinline__ float tanh_fast(float x){ float e=__expf(2.f*x); return 1.f - 2.f/(e+1.f); }

// W0 slice blocks: [j 0..15][r 0..3][kc 0..9][lane 0..63][8]
// tile row tr = lane&15 -> gate = tr&3, h_local = tr>>2 ; global row = gate*256 + j*16 + r*4 + h_local
// k = kc*32 + (lane>>4)*8 + jj ; K layout = [x(64) | h0(256)]
__global__ void prep_w0(const float* __restrict__ Wih, const float* __restrict__ Whh,
                        half_t* __restrict__ dst){
  int idx = blockIdx.x*blockDim.x + threadIdx.x;
  if (idx >= 16*4*10*64) return;
  int lane = idx & 63;
  int kc = (idx >> 6) % 10;
  int r  = (idx / 640) & 3;
  int j  = idx / 2560;
  int tr = lane & 15, kg = lane >> 4;
  int grow = (tr&3)*256 + j*16 + r*4 + (tr>>2);
  int k0 = kc*32 + kg*8;
  half_t* d = dst + (size_t)idx*8;
#pragma unroll
  for (int jj=0;jj<8;jj++){
    int k = k0 + jj;
    float v = (k < 64) ? Wih[grow*64 + k] : Whh[grow*256 + (k - 64)];
    d[jj] = (half_t)v;
  }
}

// W1 slice blocks: [j][r][kc 0..15][lane][8], K layout = [h0(256) | h1(256)]
__global__ void prep_w1(const float* __restrict__ Wih, const float* __restrict__ Whh,
                        half_t* __restrict__ dst){
  int idx = blockIdx.x*blockDim.x + threadIdx.x;
  if (idx >= 16*4*16*64) return;
  int lane = idx & 63;
  int kc = (idx >> 6) & 15;
  int r  = (idx >> 10) & 3;
  int j  = idx >> 12;
  int tr = lane & 15, kg = lane >> 4;
  int grow = (tr&3)*256 + j*16 + r*4 + (tr>>2);
  int k0 = kc*32 + kg*8;
  half_t* d = dst + (size_t)idx*8;
#pragma unroll
  for (int jj=0;jj<8;jj++){
    int k = k0 + jj;
    float v = (k < 256) ? Wih[grow*256 + k] : Whh[grow*256 + (k - 256)];
    d[jj] = (half_t)v;
  }
}

// x -> [t][g][row8 0..7][b 0..31][8] fp16
__global__ void prep_x(const float* __restrict__ x, half_t* __restrict__ xblk){
  int idx = blockIdx.x*blockDim.x + threadIdx.x;
  if (idx >= 512*8*8*32) return;
  int b = idx & 31;
  int row8 = (idx >> 5) & 7;
  int g = (idx >> 8) & 7;
  int t = idx >> 11;
  const float* src = x + ((size_t)(g*32+b)*512 + (size_t)t)*64 + row8*8;
  half_t* d = xblk + (size_t)idx*8;
#pragma unroll
  for (int jj=0;jj<8;jj++) d[jj] = (half_t)src[jj];
}

// persistent distributed 2-layer LSTM, flagless stamped exchange
__global__ __launch_bounds__(THREADS) void lstm_dist(
    const half_t* __restrict__ W0blk, const half_t* __restrict__ W1blk,
    const half_t* __restrict__ xblk,
    u32* __restrict__ h0x, u32* __restrict__ h1x,
    const float* __restrict__ b_ih0, const float* __restrict__ b_hh0,
    const float* __restrict__ b_ih1, const float* __restrict__ b_hh1,
    const float* __restrict__ W_head, const float* __restrict__ b_head,
    float* __restrict__ out)
{
  extern __shared__ char smem[];
  half_t* hbuf = (half_t*)smem;   // [2 bufs][h0:8192 | h1:8192] halves = 65536 B

  const int tid = threadIdx.x;
  const int wave = tid >> 6, lane = tid & 63;
  const int lcol = lane & 15, lrow = lane >> 4;
  const int bid = blockIdx.x;
  const int g = bid >> 4, j = bid & 15;
  const int r = wave >> 1, bt = wave & 1;
  const int bcol = bt*16 + lcol;        // batch col within group (0..31)
  const int hidx = j*16 + r*4 + lrow;   // this lane's h index (0..255)
  const int eidx = ((hidx>>3)*32 + bcol)*8 + (hidx&7);  // exchange u32 index

  // ---- one-time: A-fragments + biases into registers ----
  half8 a0[10], a1[16];
#pragma unroll
  for (int kc = 0; kc < 10; ++kc)
    a0[kc] = *(const half8*)(W0blk + ((size_t)((j*4 + r)*10 + kc)*64 + lane)*8);
#pragma unroll
  for (int kc = 0; kc < 16; ++kc)
    a1[kc] = *(const half8*)(W1blk + ((size_t)((j*4 + r)*16 + kc)*64 + lane)*8);
  f32x4 bias0, bias1;
#pragma unroll
  for (int ri = 0; ri < 4; ++ri){
    int grow = ri*256 + j*16 + r*4 + lrow;
    bias0[ri] = b_ih0[grow] + b_hh0[grow];
    bias1[ri] = b_ih1[grow] + b_hh1[grow];
  }

  // zero buf0 (h0(-1)=0, h1(-1)=0)
  for (int i = tid; i < 8192; i += THREADS) ((u32*)hbuf)[i] = 0u;

  half8 xf0, xf1;
  {
    const half_t* xs = xblk + ((size_t)0*8 + g)*2048;
    xf0 = *(const half8*)(xs + ((0*4 + lrow)*32 + bcol)*8);
    xf1 = *(const half8*)(xs + ((1*4 + lrow)*32 + bcol)*8);
  }
  __syncthreads();

  float c0 = 0.f, c1 = 0.f;

  for (int p = 0; p <= TSTEPS; ++p){
    const half_t* cb = hbuf + (size_t)(p&1)*16384;

    // B-fragments from LDS (h0 shared by L0 and L1)
    half8 h0f[8], h1f[8];
#pragma unroll
    for (int c = 0; c < 8; ++c){
      h0f[c] = *(const half8*)(cb + ((c*4 + lrow)*32 + bcol)*8);
      h1f[c] = *(const half8*)(cb + 8192 + ((c*4 + lrow)*32 + bcol)*8);
    }

    // ---- L0: step p ----
    if (p < TSTEPS){
      f32x4 acc = bias0;
      acc = __builtin_amdgcn_mfma_f32_16x16x32_f16(a0[0], xf0, acc, 0, 0, 0);
      acc = __builtin_amdgcn_mfma_f32_16x16x32_f16(a0[1], xf1, acc, 0, 0, 0);
#pragma unroll
      for (int kc = 2; kc < 10; ++kc)
        acc = __builtin_amdgcn_mfma_f32_16x16x32_f16(a0[kc], h0f[kc-2], acc, 0, 0, 0);
      float ig = sigm(acc[0]), fg = sigm(acc[1]);
      float gg = tanh_fast(acc[2]), og = sigm(acc[3]);
      c0 = fg*c0 + ig*gg;
      float hv = og * tanh_fast(c0);
      u32 sv = ((u32)(p+1) << 16) | (u32)__builtin_bit_cast(unsigned short, (half_t)hv);
      __hip_atomic_store(h0x + ((size_t)(p&1)*GROUPS + g)*8192 + eidx, sv,
                         __ATOMIC_RELAXED, __HIP_MEMORY_SCOPE_AGENT);
    }

    // ---- L1: step p-1 ----
    if (p >= 1){
      f32x4 acc = bias1;
#pragma unroll
      for (int kc = 0; kc < 8; ++kc)
        acc = __builtin_amdgcn_mfma_f32_16x16x32_f16(a1[kc], h0f[kc], acc, 0, 0, 0);
#pragma unroll
      for (int kc = 8; kc < 16; ++kc)
        acc = __builtin_amdgcn_mfma_f32_16x16x32_f16(a1[kc], h1f[kc-8], acc, 0, 0, 0);
      float ig = sigm(acc[0]), fg = sigm(acc[1]);
      float gg = tanh_fast(acc[2]), og = sigm(acc[3]);
      c1 = fg*c1 + ig*gg;
      float hv = og * tanh_fast(c1);
      u32 sv = ((u32)(p+1) << 16) | (u32)__builtin_bit_cast(unsigned short, (half_t)hv);
      __hip_atomic_store(h1x + ((size_t)(p&1)*GROUPS + g)*8192 + eidx, sv,
                         __ATOMIC_RELAXED, __HIP_MEMORY_SCOPE_AGENT);
    }

    if (p == TSTEPS) break;

    // prefetch x(p+1)
    if (p + 1 < TSTEPS){
      const half_t* xs = xblk + ((size_t)(p+1)*8 + g)*2048;
      xf0 = *(const half8*)(xs + ((0*4 + lrow)*32 + bcol)*8);
      xf1 = *(const half8*)(xs + ((1*4 + lrow)*32 + bcol)*8);
    }

    // ---- stage h0(p), h1(p-1) into buf[(p+1)&1] (stamped poll, coalesced) ----
    {
      const u32 want = (u32)(p+1);
      half_t* d0 = hbuf + (size_t)((p+1)&1)*16384;
      half_t* d1 = d0 + 8192;

      const u64* s0 = (const u64*)(h0x + ((size_t)(p&1)*GROUPS + g)*8192);
      u64 v[8];
      bool ok = false;
      for (int tries = 0; tries < (1<<20) && !ok; ++tries){
        ok = true;
#pragma unroll
        for (int i = 0; i < 8; ++i)
          v[i] = __hip_atomic_load(s0 + wave*512 + i*64 + lane,
                                   __ATOMIC_RELAXED, __HIP_MEMORY_SCOPE_AGENT);
#pragma unroll
        for (int i = 0; i < 8; ++i)
          ok = ok && ((((u32)(v[i] >> 16)) & 0xFFFFu) == want)
                  && (((u32)(v[i] >> 48)) == want);
      }
#pragma unroll
      for (int i = 0; i < 8; ++i){
        u32 pk = ((u32)(v[i] & 0xFFFFu)) | (((u32)((v[i] >> 32) & 0xFFFFu)) << 16);
        *(u32*)(d0 + (size_t)(wave*512 + i*64 + lane)*2) = pk;
      }

      if (p == 0){
#pragma unroll
        for (int i = 0; i < 8; ++i)
          *(u32*)(d1 + (size_t)(wave*512 + i*64 + lane)*2) = 0u;
      } else {
        const u64* s1 = (const u64*)(h1x + ((size_t)(p&1)*GROUPS + g)*8192);
        ok = false;
        for (int tries = 0; tries < (1<<20) && !ok; ++tries){
          ok = true;
#pragma unroll
          for (int i = 0; i < 8; ++i)
            v[i] = __hip_atomic_load(s1 + wave*512 + i*64 + lane,
                                     __ATOMIC_RELAXED, __HIP_MEMORY_SCOPE_AGENT);
#pragma unroll
          for (int i = 0; i < 8; ++i)
            ok = ok && ((((u32)(v[i] >> 16)) & 0xFFFFu) == want)
                    && (((u32)(v[i] >> 48)) == want);
        }
#pragma unroll
        for (int i = 0; i < 8; ++i){
          u32 pk = ((u32)(v[i] & 0xFFFFu)) | (((u32)((v[i] >> 32) & 0xFFFFu)) << 16);
          *(u32*)(d1 + (size_t)(wave*512 + i*64 + lane)*2) = pk;
        }
      }
    }
    __syncthreads();
  }

  __syncthreads();  // all compute reads of buf0 done before head staging overwrites it

  // ---- head: poll final h1(511) (slot 0, stamp 513) into buf0, then GEMV ----
  {
    const u64* s = (const u64*)(h1x + ((size_t)0*GROUPS + g)*8192);
    const u32 want = (u32)(TSTEPS + 1);
    u64 v[8];
    bool ok = false;
    for (int tries = 0; tries < (1<<20) && !ok; ++tries){
      ok = true;
#pragma unroll
      for (int i = 0; i < 8; ++i)
        v[i] = __hip_atomic_load(s + wave*512 + i*64 + lane,
                                 __ATOMIC_RELAXED, __HIP_MEMORY_SCOPE_AGENT);
#pragma unroll
      for (int i = 0; i < 8; ++i)
        ok = ok && ((((u32)(v[i] >> 16)) & 0xFFFFu) == want)
                && (((u32)(v[i] >> 48)) == want);
    }
#pragma unroll
    for (int i = 0; i < 8; ++i){
      u32 pk = ((u32)(v[i] & 0xFFFFu)) | (((u32)((v[i] >> 32) & 0xFFFFu)) << 16);
      *(u32*)(hbuf + (size_t)(wave*512 + i*64 + lane)*2) = pk;
    }
    __syncthreads();
    if (tid < 240){
      int bl = 2*j + (tid >= 120 ? 1 : 0);
      int o = tid % 120;
      float s2 = b_head[o];
      const float* wr = W_head + (size_t)o*256;
#pragma unroll 4
      for (int k8 = 0; k8 < 32; ++k8){
        half8 hv = *(const half8*)(hbuf + (k8*32 + bl)*8);
#pragma unroll
        for (int jj = 0; jj < 8; ++jj)
          s2 += (float)hv[jj] * wr[k8*8 + jj];
      }
      out[((size_t)g*32 + bl)*120 + o] = s2;
    }
  }
}

extern "C" void kernel_launch(void* const* d_in, const int* in_sizes, int n_in,
                              void* d_out, int out_size, void* d_ws, size_t ws_size,
                              hipStream_t stream){
  const float* x     = (const float*)d_in[0];
  const float* W_ih0 = (const float*)d_in[1];
  const float* W_hh0 = (const float*)d_in[2];
  const float* b_ih0 = (const float*)d_in[3];
  const float* b_hh0 = (const float*)d_in[4];
  const float* W_ih1 = (const float*)d_in[5];
  const float* W_hh1 = (const float*)d_in[6];
  const float* b_ih1 = (const float*)d_in[7];
  const float* b_hh1 = (const float*)d_in[8];
  const float* W_head= (const float*)d_in[9];
  const float* b_head= (const float*)d_in[10];
  float* out = (float*)d_out;

  half_t* W0blk = (half_t*)d_ws;
  half_t* W1blk = W0blk + W0_HALVES;
  half_t* xblk  = W1blk + W1_HALVES;
  u32*    h0x   = (u32*)(xblk + X_HALVES);
  u32*    h1x   = h0x + HX_U32;
  // total ws use: 18.5 MB + 1 MB exchange

  // zero stamped exchange buffers every launch (graph-replay safe: stamps restart)
  (void)hipMemsetAsync(h0x, 0, (size_t)HX_U32*2*4, stream);   // h0x + h1x contiguous

  hipLaunchKernelGGL(prep_w0, dim3(160), dim3(256), 0, stream, W_ih0, W_hh0, W0blk);
  hipLaunchKernelGGL(prep_w1, dim3(256), dim3(256), 0, stream, W_ih1, W_hh1, W1blk);
  hipLaunchKernelGGL(prep_x,  dim3(4096), dim3(256), 0, stream, x, xblk);

  (void)hipFuncSetAttribute((const void*)lstm_dist,
                            hipFuncAttributeMaxDynamicSharedMemorySize, 65536);

  hipLaunchKernelGGL(lstm_dist, dim3(NWG), dim3(THREADS), 65536, stream,
                     W0blk, W1blk, xblk, h0x, h1x,
                     b_ih0, b_hh0, b_ih1, b_hh1, W_head, b_head, out);
}